// Round 12
// baseline (190.695 us; speedup 1.0000x reference)
//
#include <hip/hip_runtime.h>
#include <hip/hip_bf16.h>
#include <stdint.h>

// Problem dims (fixed by setup_inputs)
#define B_    4
#define N_    16384
#define M_    4096
#define C1_   64
#define C2_   256
#define CIN_  320   // C2 + C1 (concat order: [interp(256), fine(64)])
#define H1_   256
#define H2_   128
#define ROWS_ (B_*N_)   // 65536
#define SPLIT_ 8
#define CHUNK_ (M_/SPLIT_)   // 512

typedef __attribute__((ext_vector_type(8))) short bf16x8;
typedef __attribute__((ext_vector_type(4))) float f32x4;
typedef __attribute__((ext_vector_type(8))) unsigned short u16x8;
typedef __attribute__((ext_vector_type(4))) unsigned short u16x4;

static __device__ __forceinline__ unsigned short f2bf(float f) {
  union { float f; unsigned u; } v; v.f = f;
  unsigned r = v.u + 0x7fffu + ((v.u >> 16) & 1u);
  return (unsigned short)(r >> 16);
}
static __device__ __forceinline__ float bf2f(unsigned short h) {
  union { unsigned u; float f; } v; v.u = ((unsigned)h) << 16;
  return v.f;
}

// async global->LDS, 16B per lane. lds base must be wave-uniform.
static __device__ __forceinline__ void gload16(const void* g, void* lds) {
  __builtin_amdgcn_global_load_lds(
      (__attribute__((address_space(1))) void*)(uintptr_t)g,
      (__attribute__((address_space(3))) void*)(uintptr_t)lds,
      16, 0, 0);
}

// strict-< top-3 insert: ties keep the earlier (lower-index) entry, matching
// jax.lax.top_k stability when candidates are presented in ascending index order.
#define INS3(dv, iv) do {                                        \
  float _d = (dv); int _ii = (iv);                               \
  if (_d < d3) {                                                 \
    if (_d < d2) {                                               \
      d3 = d2; i3 = i2;                                          \
      if (_d < d1) { d2 = d1; i2 = i1; d1 = _d; i1 = _ii; }      \
      else         { d2 = _d; i2 = _ii; }                        \
    } else { d3 = _d; i3 = _ii; }                                \
  } } while (0)

// ---------------- kernel 0: weights + coarse feats -> bf16, pts -> float4 --
__global__ __launch_bounds__(256) void prep(
    const float* __restrict__ W1, const float* __restrict__ W2,
    const float* __restrict__ xyzc, const float* __restrict__ fc,
    unsigned short* __restrict__ W1b, unsigned short* __restrict__ W2b,
    float4* __restrict__ cpk, unsigned short* __restrict__ fcb)
{
  int i = blockIdx.x * 256 + threadIdx.x;
  if (i < H1_*CIN_) W1b[i] = f2bf(W1[i]);
  if (i < H2_*H1_)  W2b[i] = f2bf(W2[i]);
  if (i < B_*M_) {
    float x = xyzc[i*3], y = xyzc[i*3+1], z = xyzc[i*3+2];
    cpk[i] = make_float4(x, y, z, x*x + y*y + z*z);
  }
  // coarse features fp32 -> bf16 (halves nn_finish gather traffic)
  const int total4 = B_*M_*C2_/4;
  const int stride = gridDim.x * 256;
  for (int t = i; t < total4; t += stride) {
    float4 v = ((const float4*)fc)[t];
    u16x4 o;
    o[0] = f2bf(v.x); o[1] = f2bf(v.y); o[2] = f2bf(v.z); o[3] = f2bf(v.w);
    ((u16x4*)fcb)[t] = o;
  }
}

// ---------------- kernel 1a: partial 3-NN over a 512-pt coarse chunk -------
// grid: B * 64 * SPLIT blocks (2048), 256 thr. 8KB LDS -> high occupancy.
// Branch-free 3-stage paired min/max sorting network, ONE live vcc at a
// time (R10's two live masks cost mask-shuffle overhead). Scan orders by
// d' = d - xx (per-lane constant shift: order-identical; final d = d'+xx is
// bit-identical to the previous kernel's fl(xx + d')). Ties: c-strict-<
// demotes the newcomer => earlier index wins, exactly INS3 semantics.
__global__ __launch_bounds__(256) void nn_scan(
    const float* __restrict__ xyzf, const float4* __restrict__ cpk,
    float4* __restrict__ pdw, int4* __restrict__ piw)
{
  __shared__ float4 cp[CHUNK_];
  const int tid  = threadIdx.x;
  const int s    = blockIdx.x & (SPLIT_-1);
  const int tile = (blockIdx.x >> 3) & 63;
  const int b    = blockIdx.x >> 9;

  const float4* src = cpk + (size_t)b * M_ + s * CHUNK_;
  for (int i = tid; i < CHUNK_; i += 256) cp[i] = src[i];
  __syncthreads();

  const int p = tile * 256 + tid;
  const size_t gp = (size_t)b * N_ + p;
  const float* xf = xyzf + gp * 3;
  const float fx = xf[0], fy = xf[1], fz = xf[2];
  const float xx = fx*fx + fy*fy + fz*fz;
  const float nx = -2.f*fx, ny = -2.f*fy, nz = -2.f*fz;

  float d1 = 3.4e38f, d2 = 3.4e38f, d3 = 3.4e38f;
  int   i1 = 0, i2 = 0, i3 = 0;

  #pragma unroll 1
  for (int g = 0; g < CHUNK_; g += 8) {
    float dd[8];
    #pragma unroll
    for (int u = 0; u < 8; ++u) {
      float4 c = cp[g + u];
      dd[u] = fmaf(nx, c.x, fmaf(ny, c.y, fmaf(nz, c.z, c.w)));  // d' = d - xx
    }
    #pragma unroll
    for (int u = 0; u < 8; ++u) {
      float d = dd[u]; int j = g + u;
      // stage 1: (k1, cand) -> k1 = min, carry h1 = max
      bool c1 = d < d1;
      float h1d = c1 ? d1 : d;   int h1i = c1 ? i1 : j;
      d1       = c1 ? d  : d1;   i1      = c1 ? j  : i1;
      // stage 2: (k2, h1) -> k2 = min, carry h2 = max
      bool c2 = h1d < d2;
      float h2d = c2 ? d2  : h1d; int h2i = c2 ? i2  : h1i;
      d2       = c2 ? h1d : d2;   i2      = c2 ? h1i : i2;
      // stage 3: k3 = min(k3, h2)
      bool c3 = h2d < d3;
      d3 = c3 ? h2d : d3;         i3 = c3 ? h2i : i3;
    }
  }
  const int base = s * CHUNK_;
  pdw[(size_t)s * ROWS_ + gp] = make_float4(d1 + xx, d2 + xx, d3 + xx, 0.f);
  piw[(size_t)s * ROWS_ + gp] = make_int4(i1 + base, i2 + base, i3 + base, 0);
}

// ---------------- kernel 1b: merge partials + weights + interp + concat ----
// grid: B * 256 blocks (1024), 256 thr; each block owns 64 fine points.
__global__ __launch_bounds__(256) void nn_finish(
    const float4* __restrict__ pdw, const int4* __restrict__ piw,
    const float* __restrict__ ff, const unsigned short* __restrict__ fcb,
    unsigned short* __restrict__ X)
{
  __shared__ float wv[64][3];
  __shared__ int   wi[64][3];
  const int tid  = threadIdx.x;
  const int b    = blockIdx.x >> 8;
  const int tile = blockIdx.x & 255;
  const size_t gp0 = (size_t)b * N_ + tile * 64;

  if (tid < 64) {
    const size_t gp = gp0 + tid;
    float d1 = 3.4e38f, d2 = 3.4e38f, d3 = 3.4e38f;
    int   i1 = 0, i2 = 0, i3 = 0;
    #pragma unroll
    for (int s = 0; s < SPLIT_; ++s) {
      float4 dv = pdw[(size_t)s * ROWS_ + gp];
      int4   iv = piw[(size_t)s * ROWS_ + gp];
      INS3(dv.x, iv.x);
      INS3(dv.y, iv.y);
      INS3(dv.z, iv.z);
    }
    d1 = fmaxf(d1, 1e-10f); d2 = fmaxf(d2, 1e-10f); d3 = fmaxf(d3, 1e-10f);
    float u1 = 1.f/d1, u2 = 1.f/d2, u3 = 1.f/d3;
    float inv = 1.f/(u1 + u2 + u3);
    wv[tid][0] = u1*inv; wv[tid][1] = u2*inv; wv[tid][2] = u3*inv;
    wi[tid][0] = i1;     wi[tid][1] = i2;     wi[tid][2] = i3;
  }
  __syncthreads();

  // interp: wave per group of 16 points; lane l covers channels 4l..4l+3.
  const int w = tid >> 6, l = tid & 63;
  const unsigned short* fcb_b = fcb + (size_t)b * M_ * C2_;
  unsigned short* Xb = X + gp0 * CIN_;
  #pragma unroll 2
  for (int q = 0; q < 16; ++q) {
    int pl = w * 16 + q;
    float a1 = wv[pl][0], a2 = wv[pl][1], a3 = wv[pl][2];
    int   j1 = wi[pl][0], j2 = wi[pl][1], j3 = wi[pl][2];
    u16x4 r1 = ((const u16x4*)(fcb_b + (size_t)j1 * C2_))[l];
    u16x4 r2 = ((const u16x4*)(fcb_b + (size_t)j2 * C2_))[l];
    u16x4 r3 = ((const u16x4*)(fcb_b + (size_t)j3 * C2_))[l];
    u16x4 o;
    #pragma unroll
    for (int e = 0; e < 4; ++e) {
      float v = fmaf(a1, bf2f(r1[e]), fmaf(a2, bf2f(r2[e]), a3 * bf2f(r3[e])));
      o[e] = f2bf(v);
    }
    *(u16x4*)(Xb + (size_t)pl * CIN_ + l * 4) = o;
  }

  // fine-feature concat: thread t -> point t>>2, 16 channels.
  {
    const float* ffb = ff + gp0 * C1_;
    int pl = tid >> 2, c0 = (tid & 3) * 16;
    const float4* fsrc = (const float4*)(ffb + (size_t)pl * C1_ + c0);
    unsigned short* dst = Xb + (size_t)pl * CIN_ + C2_ + c0;
    #pragma unroll
    for (int t = 0; t < 4; ++t) {
      float4 v = fsrc[t];
      u16x4 o;
      o[0] = f2bf(v.x); o[1] = f2bf(v.y); o[2] = f2bf(v.z); o[3] = f2bf(v.w);
      *(u16x4*)(dst + t * 4) = o;
    }
  }
}

// ---------------- GEMM: C[M][NTOT] = A[M][K] * Bw[NTOT][K]^T + col stats ---
// 128x128 tile, BK=64, 4 waves (2x2), 16x16x32 bf16 MFMA, fp32 acc.
// For NCT==2: XCD-pair swizzle -- blocks b and b+8 (same XCD under %8
// round-robin) share one A-tile, so the second read hits that XCD's L2.
template<int K, int NTOT, bool OUTBF>
__global__ __launch_bounds__(256) void gemm_stats(
    const unsigned short* __restrict__ A,
    const unsigned short* __restrict__ Bw,
    unsigned short* __restrict__ Yb,
    float* __restrict__ Yf,
    float* __restrict__ part)
{
  constexpr int BM = 128, BN = 128, BK = 64;
  constexpr int NCT = NTOT / BN;
  __shared__ unsigned short As[BM*BK];
  __shared__ unsigned short Bs[BN*BK];
  __shared__ float sred[2][BN][2];

  const int tid = threadIdx.x;
  const int l   = tid & 63;
  const int w   = tid >> 6;
  const int wm  = w >> 1, wn = w & 1;
  int rt, ct;
  if (NCT == 2) {
    rt = (blockIdx.x & 7) | ((blockIdx.x >> 4) << 3);
    ct = (blockIdx.x >> 3) & 1;
  } else {
    rt = blockIdx.x / NCT; ct = blockIdx.x % NCT;
  }
  const int lr  = l & 15;
  const int lk  = (l >> 4) * 8;

  const unsigned short* Arow = A  + (size_t)rt * BM * K;
  const unsigned short* Brow = Bw + (size_t)ct * BN * K;

  f32x4 acc[4][4] = {};

  for (int k0 = 0; k0 < K; k0 += BK) {
    #pragma unroll
    for (int q = 0; q < 4; ++q) {
      int chunk = q * 256 + tid;
      int row = chunk >> 3, cc = chunk & 7;
      unsigned ldsoff = (unsigned)(q * 256 + (tid & ~63)) * 16u;   // wave-uniform
      gload16(Arow + (size_t)row * K + k0 + cc * 8, (char*)As + ldsoff);
      gload16(Brow + (size_t)row * K + k0 + cc * 8, (char*)Bs + ldsoff);
    }
    __syncthreads();
    #pragma unroll
    for (int kk = 0; kk < BK/32; ++kk) {
      bf16x8 af[4], bfr[4];
      #pragma unroll
      for (int m = 0; m < 4; ++m)
        af[m] = *(const bf16x8*)(As + (wm*64 + m*16 + lr)*BK + kk*32 + lk);
      #pragma unroll
      for (int n = 0; n < 4; ++n)
        bfr[n] = *(const bf16x8*)(Bs + (wn*64 + n*16 + lr)*BK + kk*32 + lk);
      #pragma unroll
      for (int m = 0; m < 4; ++m)
        #pragma unroll
        for (int n = 0; n < 4; ++n)
          acc[m][n] = __builtin_amdgcn_mfma_f32_16x16x32_bf16(af[m], bfr[n], acc[m][n], 0, 0, 0);
    }
    __syncthreads();
  }

  // epilogue: store C (fp32 acc -> bf16 or fp32) + column sums/sumsq
  const int orow0 = rt*BM + wm*64;
  const int ocol0 = ct*BN + wn*64;
  #pragma unroll
  for (int n = 0; n < 4; ++n) {
    float s = 0.f, qq = 0.f;
    #pragma unroll
    for (int m = 0; m < 4; ++m) {
      #pragma unroll
      for (int r = 0; r < 4; ++r) {
        float v = acc[m][n][r];
        int row = orow0 + m*16 + (l >> 4)*4 + r;
        int col = ocol0 + n*16 + lr;
        size_t off = (size_t)row * NTOT + col;
        if (OUTBF) Yb[off] = f2bf(v); else Yf[off] = v;
        s += v; qq += v*v;
      }
    }
    s  += __shfl_xor(s, 16);  s  += __shfl_xor(s, 32);
    qq += __shfl_xor(qq, 16); qq += __shfl_xor(qq, 32);
    if (l < 16) {
      sred[wm][wn*64 + n*16 + l][0] = s;
      sred[wm][wn*64 + n*16 + l][1] = qq;
    }
  }
  __syncthreads();
  if (tid < BN) {
    float S = sred[0][tid][0] + sred[1][tid][0];
    float Q = sred[0][tid][1] + sred[1][tid][1];
    part[((size_t)rt * NTOT + ct*BN + tid) * 2 + 0] = S;
    part[((size_t)rt * NTOT + ct*BN + tid) * 2 + 1] = Q;
  }
}

// ---------------- GEMM2 with BN+ReLU fused on the A operand ----------------
// A[row][k] = bf16(relu(a[k]*Yin[row][k] + b[k])) computed during reg-staged
// A-load; B stays global_load_lds. Output Y2 stored as bf16 (stats from the
// exact fp32 accumulator; bf16 store halves bnrelu_out's read traffic).
template<int K, int NTOT>
__global__ __launch_bounds__(256) void gemm_bnrelu_stats(
    const unsigned short* __restrict__ Yin,
    const float* __restrict__ ab,
    const unsigned short* __restrict__ Bw,
    unsigned short* __restrict__ Yb,
    float* __restrict__ part)
{
  constexpr int BM = 128, BN = 128, BK = 64;
  constexpr int NCT = NTOT / BN;
  __shared__ unsigned short As[BM*BK];
  __shared__ unsigned short Bs[BN*BK];
  __shared__ float sa[K], sb[K];
  __shared__ float sred[2][BN][2];

  const int tid = threadIdx.x;
  const int l   = tid & 63;
  const int w   = tid >> 6;
  const int wm  = w >> 1, wn = w & 1;
  const int rt  = blockIdx.x / NCT, ct = blockIdx.x % NCT;
  const int lr  = l & 15;
  const int lk  = (l >> 4) * 8;
  const int cc  = tid & 7;      // k-subchunk, fixed per thread
  const int r0  = tid >> 3;     // row base within q-group

  // stage BN coeffs (K == 256 == blockDim)
  sa[tid] = ab[tid*2];
  sb[tid] = ab[tid*2 + 1];

  const unsigned short* Arow = Yin + (size_t)rt * BM * K;
  const unsigned short* Brow = Bw  + (size_t)ct * BN * K;

  f32x4 acc[4][4] = {};
  __syncthreads();   // sa/sb visible

  for (int k0 = 0; k0 < K; k0 += BK) {
    // B tile: async direct-to-LDS
    #pragma unroll
    for (int q = 0; q < 4; ++q) {
      int chunk = q * 256 + tid;
      int row = chunk >> 3, c8 = chunk & 7;
      unsigned ldsoff = (unsigned)(q * 256 + (tid & ~63)) * 16u;
      gload16(Brow + (size_t)row * K + k0 + c8 * 8, (char*)Bs + ldsoff);
    }
    // A tile: reg-staged with BN+ReLU transform
    float a_[8], b_[8];
    *(float4*)&a_[0] = *(const float4*)&sa[k0 + cc*8];
    *(float4*)&a_[4] = *(const float4*)&sa[k0 + cc*8 + 4];
    *(float4*)&b_[0] = *(const float4*)&sb[k0 + cc*8];
    *(float4*)&b_[4] = *(const float4*)&sb[k0 + cc*8 + 4];
    #pragma unroll
    for (int q = 0; q < 4; ++q) {
      int row = q*32 + r0;
      u16x8 v = *(const u16x8*)(Arow + (size_t)row * K + k0 + cc*8);
      u16x8 o;
      #pragma unroll
      for (int e = 0; e < 8; ++e) {
        float f = fmaxf(fmaf(bf2f((unsigned short)v[e]), a_[e], b_[e]), 0.f);
        o[e] = f2bf(f);
      }
      *(u16x8*)((char*)As + (unsigned)(q*256 + tid) * 16u) = o;
    }
    __syncthreads();
    #pragma unroll
    for (int kk = 0; kk < BK/32; ++kk) {
      bf16x8 af[4], bfr[4];
      #pragma unroll
      for (int m = 0; m < 4; ++m)
        af[m] = *(const bf16x8*)(As + (wm*64 + m*16 + lr)*BK + kk*32 + lk);
      #pragma unroll
      for (int n = 0; n < 4; ++n)
        bfr[n] = *(const bf16x8*)(Bs + (wn*64 + n*16 + lr)*BK + kk*32 + lk);
      #pragma unroll
      for (int m = 0; m < 4; ++m)
        #pragma unroll
        for (int n = 0; n < 4; ++n)
          acc[m][n] = __builtin_amdgcn_mfma_f32_16x16x32_bf16(af[m], bfr[n], acc[m][n], 0, 0, 0);
    }
    __syncthreads();
  }

  // epilogue: store bf16 + column sums/sumsq (stats from fp32 acc)
  const int orow0 = rt*BM + wm*64;
  const int ocol0 = ct*BN + wn*64;
  #pragma unroll
  for (int n = 0; n < 4; ++n) {
    float s = 0.f, qq = 0.f;
    #pragma unroll
    for (int m = 0; m < 4; ++m) {
      #pragma unroll
      for (int r = 0; r < 4; ++r) {
        float v = acc[m][n][r];
        int row = orow0 + m*16 + (l >> 4)*4 + r;
        int col = ocol0 + n*16 + lr;
        Yb[(size_t)row * NTOT + col] = f2bf(v);
        s += v; qq += v*v;
      }
    }
    s  += __shfl_xor(s, 16);  s  += __shfl_xor(s, 32);
    qq += __shfl_xor(qq, 16); qq += __shfl_xor(qq, 32);
    if (l < 16) {
      sred[wm][wn*64 + n*16 + l][0] = s;
      sred[wm][wn*64 + n*16 + l][1] = qq;
    }
  }
  __syncthreads();
  if (tid < BN) {
    float S = sred[0][tid][0] + sred[1][tid][0];
    float Q = sred[0][tid][1] + sred[1][tid][1];
    part[((size_t)rt * NTOT + ct*BN + tid) * 2 + 0] = S;
    part[((size_t)rt * NTOT + ct*BN + tid) * 2 + 1] = Q;
  }
}

// ---------------- finalize: per-channel partials -> (a,b) BN coeffs -------
__global__ void finalize_stats(const float* __restrict__ part,
                               const float* __restrict__ g,
                               const float* __restrict__ be,
                               float* __restrict__ ab, int nrt, int C, float invM)
{
  const int c = blockIdx.x;
  const int t = threadIdx.x;
  float s = 0.f, q = 0.f;
  for (int r = t; r < nrt; r += 64) {
    s += part[((size_t)r * C + c) * 2 + 0];
    q += part[((size_t)r * C + c) * 2 + 1];
  }
  #pragma unroll
  for (int o = 32; o > 0; o >>= 1) { s += __shfl_down(s, o); q += __shfl_down(q, o); }
  if (t == 0) {
    float mean = s * invM;
    float var  = q * invM - mean * mean;
    float rstd = rsqrtf(var + 1e-5f);
    float a = g[c] * rstd;
    ab[c*2 + 0] = a;
    ab[c*2 + 1] = be[c] - mean * a;
  }
}

// ---------------- elementwise BN+ReLU (bf16 in -> fp32 out) ----------------
__global__ __launch_bounds__(256) void bnrelu_out(
    const unsigned short* __restrict__ Y, const float* __restrict__ ab,
    float* __restrict__ out)
{
  __shared__ float sa[H2_], sb[H2_];
  if (threadIdx.x < H2_) { sa[threadIdx.x] = ab[threadIdx.x*2]; sb[threadIdx.x] = ab[threadIdx.x*2+1]; }
  __syncthreads();
  const size_t total = (size_t)ROWS_ * H2_ / 8;
  for (size_t i = (size_t)blockIdx.x*256 + threadIdx.x; i < total; i += (size_t)gridDim.x*256) {
    u16x8 v = ((const u16x8*)Y)[i];
    int cb = (int)((i * 8) & (H2_ - 1));
    float4 o0, o1;
    o0.x = fmaxf(fmaf(bf2f((unsigned short)v[0]), sa[cb+0], sb[cb+0]), 0.f);
    o0.y = fmaxf(fmaf(bf2f((unsigned short)v[1]), sa[cb+1], sb[cb+1]), 0.f);
    o0.z = fmaxf(fmaf(bf2f((unsigned short)v[2]), sa[cb+2], sb[cb+2]), 0.f);
    o0.w = fmaxf(fmaf(bf2f((unsigned short)v[3]), sa[cb+3], sb[cb+3]), 0.f);
    o1.x = fmaxf(fmaf(bf2f((unsigned short)v[4]), sa[cb+4], sb[cb+4]), 0.f);
    o1.y = fmaxf(fmaf(bf2f((unsigned short)v[5]), sa[cb+5], sb[cb+5]), 0.f);
    o1.z = fmaxf(fmaf(bf2f((unsigned short)v[6]), sa[cb+6], sb[cb+6]), 0.f);
    o1.w = fmaxf(fmaf(bf2f((unsigned short)v[7]), sa[cb+7], sb[cb+7]), 0.f);
    ((float4*)out)[i*2]   = o0;
    ((float4*)out)[i*2+1] = o1;
  }
}

// ---------------- launch -------------------------------------------------
extern "C" void kernel_launch(void* const* d_in, const int* in_sizes, int n_in,
                              void* d_out, int out_size, void* d_ws, size_t ws_size,
                              hipStream_t stream)
{
  const float* xyzf = (const float*)d_in[0];
  const float* xyzc = (const float*)d_in[1];
  const float* ff   = (const float*)d_in[2];
  const float* fc   = (const float*)d_in[3];
  const float* W1   = (const float*)d_in[4];
  // d_in[5] = b1 : cancels inside BatchNorm
  const float* g1   = (const float*)d_in[6];
  const float* be1  = (const float*)d_in[7];
  const float* W2   = (const float*)d_in[8];
  // d_in[9] = b2 : cancels inside BatchNorm
  const float* g2   = (const float*)d_in[10];
  const float* be2  = (const float*)d_in[11];
  float* out = (float*)d_out;

  char* ws = (char*)d_ws;
  // layout (bytes), all 256-aligned. Lifetime-based aliasing:
  //  X  @229376 : written nn_finish, read gemm1, then DEAD
  //  Y2b@229376 : written gemm2 (after gemm1 done), read bnrelu_out [alias X]
  //  fcb@42172416: written prep, read nn_finish, then DEAD
  //  Y1 @42172416: written gemm1 (after nn_finish), read gemm2     [alias fcb]
  unsigned short* W1b  = (unsigned short*)(ws + 0);          // 163840
  unsigned short* W2b  = (unsigned short*)(ws + 163840);     // 65536
  unsigned short* X    = (unsigned short*)(ws + 229376);     // 41943040
  unsigned short* Y2b  = (unsigned short*)(ws + 229376);     // 16777216 (alias X)
  unsigned short* fcb  = (unsigned short*)(ws + 42172416);   // 8388608
  unsigned short* Y1   = (unsigned short*)(ws + 42172416);   // 33554432 (alias fcb)
  float* part1 = (float*)(ws + 75726848);                    // 1048576
  float* part2 = (float*)(ws + 76775424);                    // 524288
  float* ab1   = (float*)(ws + 77299712);                    // 2048
  float* ab2   = (float*)(ws + 77301760);                    // 1024
  float4* cpk  = (float4*)(ws + 77302784);                   // 262144
  float4* pdw  = (float4*)(ws + 77564928);                   // 8388608
  int4*   piw  = (int4*)  (ws + 85953536);                   // 8388608  (end ~94.3MB)

  prep<<<1024, 256, 0, stream>>>(W1, W2, xyzc, fc, W1b, W2b, cpk, fcb);
  nn_scan<<<B_ * 64 * SPLIT_, 256, 0, stream>>>(xyzf, cpk, pdw, piw);
  nn_finish<<<B_ * 256, 256, 0, stream>>>(pdw, piw, ff, fcb, X);

  // layer 1: y1 = X @ W1^T  (M=65536, N=256, K=320), stats fused
  gemm_stats<CIN_, H1_, true><<<(ROWS_/128) * (H1_/128), 256, 0, stream>>>(
      X, W1b, Y1, nullptr, part1);
  finalize_stats<<<H1_, 64, 0, stream>>>(part1, g1, be1, ab1, ROWS_/128, H1_, 1.f/ROWS_);

  // layer 2: y2 = relu(bn1(Y1)) @ W2^T with BN+ReLU fused into the A-load
  gemm_bnrelu_stats<H1_, H2_><<<(ROWS_/128) * (H2_/128), 256, 0, stream>>>(
      Y1, ab1, W2b, Y2b, part2);
  finalize_stats<<<H2_, 64, 0, stream>>>(part2, g2, be2, ab2, ROWS_/128, H2_, 1.f/ROWS_);
  bnrelu_out<<<2048, 256, 0, stream>>>(Y2b, ab2, out);
}

// Round 13
// 163.241 us; speedup vs baseline: 1.1682x; 1.1682x over previous
//
#include <hip/hip_runtime.h>
#include <hip/hip_bf16.h>
#include <stdint.h>

// Problem dims (fixed by setup_inputs)
#define B_    4
#define N_    16384
#define M_    4096
#define C1_   64
#define C2_   256
#define CIN_  320   // C2 + C1 (concat order: [interp(256), fine(64)])
#define H1_   256
#define H2_   128
#define ROWS_ (B_*N_)   // 65536
#define SPLIT_ 4
#define CHUNK_ (M_/SPLIT_)   // 1024

typedef __attribute__((ext_vector_type(8))) short bf16x8;
typedef __attribute__((ext_vector_type(4))) float f32x4;
typedef __attribute__((ext_vector_type(8))) unsigned short u16x8;
typedef __attribute__((ext_vector_type(4))) unsigned short u16x4;

static __device__ __forceinline__ unsigned short f2bf(float f) {
  union { float f; unsigned u; } v; v.f = f;
  unsigned r = v.u + 0x7fffu + ((v.u >> 16) & 1u);
  return (unsigned short)(r >> 16);
}
static __device__ __forceinline__ float bf2f(unsigned short h) {
  union { unsigned u; float f; } v; v.u = ((unsigned)h) << 16;
  return v.f;
}

// async global->LDS, 16B per lane. lds base must be wave-uniform.
static __device__ __forceinline__ void gload16(const void* g, void* lds) {
  __builtin_amdgcn_global_load_lds(
      (__attribute__((address_space(1))) void*)(uintptr_t)g,
      (__attribute__((address_space(3))) void*)(uintptr_t)lds,
      16, 0, 0);
}

// strict-< top-3 insert: ties keep the earlier (lower-index) entry, matching
// jax.lax.top_k stability when candidates are presented in ascending index order.
#define INS3(dv, iv) do {                                        \
  float _d = (dv); int _ii = (iv);                               \
  if (_d < d3) {                                                 \
    if (_d < d2) {                                               \
      d3 = d2; i3 = i2;                                          \
      if (_d < d1) { d2 = d1; i2 = i1; d1 = _d; i1 = _ii; }      \
      else         { d2 = _d; i2 = _ii; }                        \
    } else { d3 = _d; i3 = _ii; }                                \
  } } while (0)

// ---------------- kernel 0: weights + coarse feats -> bf16, pts -> float4 --
__global__ __launch_bounds__(256) void prep(
    const float* __restrict__ W1, const float* __restrict__ W2,
    const float* __restrict__ xyzc, const float* __restrict__ fc,
    unsigned short* __restrict__ W1b, unsigned short* __restrict__ W2b,
    float4* __restrict__ cpk, unsigned short* __restrict__ fcb)
{
  int i = blockIdx.x * 256 + threadIdx.x;
  if (i < H1_*CIN_) W1b[i] = f2bf(W1[i]);
  if (i < H2_*H1_)  W2b[i] = f2bf(W2[i]);
  if (i < B_*M_) {
    float x = xyzc[i*3], y = xyzc[i*3+1], z = xyzc[i*3+2];
    cpk[i] = make_float4(x, y, z, x*x + y*y + z*z);
  }
  // coarse features fp32 -> bf16 (halves nn_finish gather traffic)
  const int total4 = B_*M_*C2_/4;
  const int stride = gridDim.x * 256;
  for (int t = i; t < total4; t += stride) {
    float4 v = ((const float4*)fc)[t];
    u16x4 o;
    o[0] = f2bf(v.x); o[1] = f2bf(v.y); o[2] = f2bf(v.z); o[3] = f2bf(v.w);
    ((u16x4*)fcb)[t] = o;
  }
}

// ---------------- kernel 1a: partial 3-NN over a 1024-pt coarse chunk ------
// grid: B * 64 * SPLIT blocks (1024), 256 thr. 16KB LDS, 4 blocks/CU.
// R10-exact structure (measured best: 78.4us at CHUNK=512): EXACT strict-<
// selection, single outer branch + flat branchless body. CHUNK=1024 lowers
// the wave-any-hit rate (~0.74 -> ~0.50), cutting amortized insert cost.
// Branchless chains / skip screens / packed keys all measured worse
// (R6 87, R7 114, R8 92, R9 wrong, R12 112).
__global__ __launch_bounds__(256) void nn_scan(
    const float* __restrict__ xyzf, const float4* __restrict__ cpk,
    float4* __restrict__ pdw, int4* __restrict__ piw)
{
  __shared__ float4 cp[CHUNK_];
  const int tid  = threadIdx.x;
  const int s    = blockIdx.x & (SPLIT_-1);
  const int tile = (blockIdx.x >> 2) & 63;
  const int b    = blockIdx.x >> 8;

  const float4* src = cpk + (size_t)b * M_ + s * CHUNK_;
  for (int i = tid; i < CHUNK_; i += 256) cp[i] = src[i];
  __syncthreads();

  const int p = tile * 256 + tid;
  const size_t gp = (size_t)b * N_ + p;
  const float* xf = xyzf + gp * 3;
  const float fx = xf[0], fy = xf[1], fz = xf[2];
  const float xx = fx*fx + fy*fy + fz*fz;
  const float nx = -2.f*fx, ny = -2.f*fy, nz = -2.f*fz;

  float d1 = 3.4e38f, d2 = 3.4e38f, d3 = 3.4e38f;
  int   i1 = 0, i2 = 0, i3 = 0;

  #pragma unroll 1
  for (int g = 0; g < CHUNK_; g += 8) {
    float dd[8];
    #pragma unroll
    for (int u = 0; u < 8; ++u) {
      float4 c = cp[g + u];
      dd[u] = xx + fmaf(nx, c.x, fmaf(ny, c.y, fmaf(nz, c.z, c.w)));
    }
    #pragma unroll
    for (int u = 0; u < 8; ++u) {
      float d = dd[u]; int j = g + u;
      if (d < d3) {                      // exact strict-<, ascending index
        bool c1 = d < d1, c2 = d < d2;
        d3 = c2 ? d2 : d;              i3 = c2 ? i2 : j;
        d2 = c1 ? d1 : (c2 ? d : d2);  i2 = c1 ? i1 : (c2 ? j : i2);
        d1 = c1 ? d  : d1;             i1 = c1 ? j  : i1;
      }
    }
  }
  const int base = s * CHUNK_;
  pdw[(size_t)s * ROWS_ + gp] = make_float4(d1, d2, d3, 0.f);
  piw[(size_t)s * ROWS_ + gp] = make_int4(i1 + base, i2 + base, i3 + base, 0);
}

// ---------------- kernel 1b: merge partials + weights + interp + concat ----
// grid: B * 256 blocks (1024), 256 thr; each block owns 64 fine points.
__global__ __launch_bounds__(256) void nn_finish(
    const float4* __restrict__ pdw, const int4* __restrict__ piw,
    const float* __restrict__ ff, const unsigned short* __restrict__ fcb,
    unsigned short* __restrict__ X)
{
  __shared__ float wv[64][3];
  __shared__ int   wi[64][3];
  const int tid  = threadIdx.x;
  const int b    = blockIdx.x >> 8;
  const int tile = blockIdx.x & 255;
  const size_t gp0 = (size_t)b * N_ + tile * 64;

  if (tid < 64) {
    const size_t gp = gp0 + tid;
    float d1 = 3.4e38f, d2 = 3.4e38f, d3 = 3.4e38f;
    int   i1 = 0, i2 = 0, i3 = 0;
    #pragma unroll
    for (int s = 0; s < SPLIT_; ++s) {
      float4 dv = pdw[(size_t)s * ROWS_ + gp];
      int4   iv = piw[(size_t)s * ROWS_ + gp];
      INS3(dv.x, iv.x);
      INS3(dv.y, iv.y);
      INS3(dv.z, iv.z);
    }
    d1 = fmaxf(d1, 1e-10f); d2 = fmaxf(d2, 1e-10f); d3 = fmaxf(d3, 1e-10f);
    float u1 = 1.f/d1, u2 = 1.f/d2, u3 = 1.f/d3;
    float inv = 1.f/(u1 + u2 + u3);
    wv[tid][0] = u1*inv; wv[tid][1] = u2*inv; wv[tid][2] = u3*inv;
    wi[tid][0] = i1;     wi[tid][1] = i2;     wi[tid][2] = i3;
  }
  __syncthreads();

  // interp: wave per group of 16 points; lane l covers channels 4l..4l+3.
  const int w = tid >> 6, l = tid & 63;
  const unsigned short* fcb_b = fcb + (size_t)b * M_ * C2_;
  unsigned short* Xb = X + gp0 * CIN_;
  #pragma unroll 2
  for (int q = 0; q < 16; ++q) {
    int pl = w * 16 + q;
    float a1 = wv[pl][0], a2 = wv[pl][1], a3 = wv[pl][2];
    int   j1 = wi[pl][0], j2 = wi[pl][1], j3 = wi[pl][2];
    u16x4 r1 = ((const u16x4*)(fcb_b + (size_t)j1 * C2_))[l];
    u16x4 r2 = ((const u16x4*)(fcb_b + (size_t)j2 * C2_))[l];
    u16x4 r3 = ((const u16x4*)(fcb_b + (size_t)j3 * C2_))[l];
    u16x4 o;
    #pragma unroll
    for (int e = 0; e < 4; ++e) {
      float v = fmaf(a1, bf2f(r1[e]), fmaf(a2, bf2f(r2[e]), a3 * bf2f(r3[e])));
      o[e] = f2bf(v);
    }
    *(u16x4*)(Xb + (size_t)pl * CIN_ + l * 4) = o;
  }

  // fine-feature concat: thread t -> point t>>2, 16 channels.
  {
    const float* ffb = ff + gp0 * C1_;
    int pl = tid >> 2, c0 = (tid & 3) * 16;
    const float4* fsrc = (const float4*)(ffb + (size_t)pl * C1_ + c0);
    unsigned short* dst = Xb + (size_t)pl * CIN_ + C2_ + c0;
    #pragma unroll
    for (int t = 0; t < 4; ++t) {
      float4 v = fsrc[t];
      u16x4 o;
      o[0] = f2bf(v.x); o[1] = f2bf(v.y); o[2] = f2bf(v.z); o[3] = f2bf(v.w);
      *(u16x4*)(dst + t * 4) = o;
    }
  }
}

// ---------------- GEMM: C[M][NTOT] = A[M][K] * Bw[NTOT][K]^T + col stats ---
// 128x128 tile, BK=64, 4 waves (2x2), 16x16x32 bf16 MFMA, fp32 acc.
// For NCT==2: XCD-pair swizzle -- blocks b and b+8 (same XCD under %8
// round-robin) share one A-tile, so the second read hits that XCD's L2.
template<int K, int NTOT, bool OUTBF>
__global__ __launch_bounds__(256) void gemm_stats(
    const unsigned short* __restrict__ A,
    const unsigned short* __restrict__ Bw,
    unsigned short* __restrict__ Yb,
    float* __restrict__ Yf,
    float* __restrict__ part)
{
  constexpr int BM = 128, BN = 128, BK = 64;
  constexpr int NCT = NTOT / BN;
  __shared__ unsigned short As[BM*BK];
  __shared__ unsigned short Bs[BN*BK];
  __shared__ float sred[2][BN][2];

  const int tid = threadIdx.x;
  const int l   = tid & 63;
  const int w   = tid >> 6;
  const int wm  = w >> 1, wn = w & 1;
  int rt, ct;
  if (NCT == 2) {
    rt = (blockIdx.x & 7) | ((blockIdx.x >> 4) << 3);
    ct = (blockIdx.x >> 3) & 1;
  } else {
    rt = blockIdx.x / NCT; ct = blockIdx.x % NCT;
  }
  const int lr  = l & 15;
  const int lk  = (l >> 4) * 8;

  const unsigned short* Arow = A  + (size_t)rt * BM * K;
  const unsigned short* Brow = Bw + (size_t)ct * BN * K;

  f32x4 acc[4][4] = {};

  for (int k0 = 0; k0 < K; k0 += BK) {
    #pragma unroll
    for (int q = 0; q < 4; ++q) {
      int chunk = q * 256 + tid;
      int row = chunk >> 3, cc = chunk & 7;
      unsigned ldsoff = (unsigned)(q * 256 + (tid & ~63)) * 16u;   // wave-uniform
      gload16(Arow + (size_t)row * K + k0 + cc * 8, (char*)As + ldsoff);
      gload16(Brow + (size_t)row * K + k0 + cc * 8, (char*)Bs + ldsoff);
    }
    __syncthreads();
    #pragma unroll
    for (int kk = 0; kk < BK/32; ++kk) {
      bf16x8 af[4], bfr[4];
      #pragma unroll
      for (int m = 0; m < 4; ++m)
        af[m] = *(const bf16x8*)(As + (wm*64 + m*16 + lr)*BK + kk*32 + lk);
      #pragma unroll
      for (int n = 0; n < 4; ++n)
        bfr[n] = *(const bf16x8*)(Bs + (wn*64 + n*16 + lr)*BK + kk*32 + lk);
      #pragma unroll
      for (int m = 0; m < 4; ++m)
        #pragma unroll
        for (int n = 0; n < 4; ++n)
          acc[m][n] = __builtin_amdgcn_mfma_f32_16x16x32_bf16(af[m], bfr[n], acc[m][n], 0, 0, 0);
    }
    __syncthreads();
  }

  // epilogue: store C (fp32 acc -> bf16 or fp32) + column sums/sumsq
  const int orow0 = rt*BM + wm*64;
  const int ocol0 = ct*BN + wn*64;
  #pragma unroll
  for (int n = 0; n < 4; ++n) {
    float s = 0.f, qq = 0.f;
    #pragma unroll
    for (int m = 0; m < 4; ++m) {
      #pragma unroll
      for (int r = 0; r < 4; ++r) {
        float v = acc[m][n][r];
        int row = orow0 + m*16 + (l >> 4)*4 + r;
        int col = ocol0 + n*16 + lr;
        size_t off = (size_t)row * NTOT + col;
        if (OUTBF) Yb[off] = f2bf(v); else Yf[off] = v;
        s += v; qq += v*v;
      }
    }
    s  += __shfl_xor(s, 16);  s  += __shfl_xor(s, 32);
    qq += __shfl_xor(qq, 16); qq += __shfl_xor(qq, 32);
    if (l < 16) {
      sred[wm][wn*64 + n*16 + l][0] = s;
      sred[wm][wn*64 + n*16 + l][1] = qq;
    }
  }
  __syncthreads();
  if (tid < BN) {
    float S = sred[0][tid][0] + sred[1][tid][0];
    float Q = sred[0][tid][1] + sred[1][tid][1];
    part[((size_t)rt * NTOT + ct*BN + tid) * 2 + 0] = S;
    part[((size_t)rt * NTOT + ct*BN + tid) * 2 + 1] = Q;
  }
}

// ---------------- GEMM2 with BN+ReLU fused on the A operand ----------------
// A[row][k] = bf16(relu(a[k]*Yin[row][k] + b[k])) computed during reg-staged
// A-load; B stays global_load_lds. Output Y2 stored as bf16 (stats from the
// exact fp32 accumulator; bf16 store halves bnrelu_out's read traffic).
template<int K, int NTOT>
__global__ __launch_bounds__(256) void gemm_bnrelu_stats(
    const unsigned short* __restrict__ Yin,
    const float* __restrict__ ab,
    const unsigned short* __restrict__ Bw,
    unsigned short* __restrict__ Yb,
    float* __restrict__ part)
{
  constexpr int BM = 128, BN = 128, BK = 64;
  constexpr int NCT = NTOT / BN;
  __shared__ unsigned short As[BM*BK];
  __shared__ unsigned short Bs[BN*BK];
  __shared__ float sa[K], sb[K];
  __shared__ float sred[2][BN][2];

  const int tid = threadIdx.x;
  const int l   = tid & 63;
  const int w   = tid >> 6;
  const int wm  = w >> 1, wn = w & 1;
  const int rt  = blockIdx.x / NCT, ct = blockIdx.x % NCT;
  const int lr  = l & 15;
  const int lk  = (l >> 4) * 8;
  const int cc  = tid & 7;      // k-subchunk, fixed per thread
  const int r0  = tid >> 3;     // row base within q-group

  // stage BN coeffs (K == 256 == blockDim)
  sa[tid] = ab[tid*2];
  sb[tid] = ab[tid*2 + 1];

  const unsigned short* Arow = Yin + (size_t)rt * BM * K;
  const unsigned short* Brow = Bw  + (size_t)ct * BN * K;

  f32x4 acc[4][4] = {};
  __syncthreads();   // sa/sb visible

  for (int k0 = 0; k0 < K; k0 += BK) {
    // B tile: async direct-to-LDS
    #pragma unroll
    for (int q = 0; q < 4; ++q) {
      int chunk = q * 256 + tid;
      int row = chunk >> 3, c8 = chunk & 7;
      unsigned ldsoff = (unsigned)(q * 256 + (tid & ~63)) * 16u;
      gload16(Brow + (size_t)row * K + k0 + c8 * 8, (char*)Bs + ldsoff);
    }
    // A tile: reg-staged with BN+ReLU transform
    float a_[8], b_[8];
    *(float4*)&a_[0] = *(const float4*)&sa[k0 + cc*8];
    *(float4*)&a_[4] = *(const float4*)&sa[k0 + cc*8 + 4];
    *(float4*)&b_[0] = *(const float4*)&sb[k0 + cc*8];
    *(float4*)&b_[4] = *(const float4*)&sb[k0 + cc*8 + 4];
    #pragma unroll
    for (int q = 0; q < 4; ++q) {
      int row = q*32 + r0;
      u16x8 v = *(const u16x8*)(Arow + (size_t)row * K + k0 + cc*8);
      u16x8 o;
      #pragma unroll
      for (int e = 0; e < 8; ++e) {
        float f = fmaxf(fmaf(bf2f((unsigned short)v[e]), a_[e], b_[e]), 0.f);
        o[e] = f2bf(f);
      }
      *(u16x8*)((char*)As + (unsigned)(q*256 + tid) * 16u) = o;
    }
    __syncthreads();
    #pragma unroll
    for (int kk = 0; kk < BK/32; ++kk) {
      bf16x8 af[4], bfr[4];
      #pragma unroll
      for (int m = 0; m < 4; ++m)
        af[m] = *(const bf16x8*)(As + (wm*64 + m*16 + lr)*BK + kk*32 + lk);
      #pragma unroll
      for (int n = 0; n < 4; ++n)
        bfr[n] = *(const bf16x8*)(Bs + (wn*64 + n*16 + lr)*BK + kk*32 + lk);
      #pragma unroll
      for (int m = 0; m < 4; ++m)
        #pragma unroll
        for (int n = 0; n < 4; ++n)
          acc[m][n] = __builtin_amdgcn_mfma_f32_16x16x32_bf16(af[m], bfr[n], acc[m][n], 0, 0, 0);
    }
    __syncthreads();
  }

  // epilogue: store bf16 + column sums/sumsq (stats from fp32 acc)
  const int orow0 = rt*BM + wm*64;
  const int ocol0 = ct*BN + wn*64;
  #pragma unroll
  for (int n = 0; n < 4; ++n) {
    float s = 0.f, qq = 0.f;
    #pragma unroll
    for (int m = 0; m < 4; ++m) {
      #pragma unroll
      for (int r = 0; r < 4; ++r) {
        float v = acc[m][n][r];
        int row = orow0 + m*16 + (l >> 4)*4 + r;
        int col = ocol0 + n*16 + lr;
        Yb[(size_t)row * NTOT + col] = f2bf(v);
        s += v; qq += v*v;
      }
    }
    s  += __shfl_xor(s, 16);  s  += __shfl_xor(s, 32);
    qq += __shfl_xor(qq, 16); qq += __shfl_xor(qq, 32);
    if (l < 16) {
      sred[wm][wn*64 + n*16 + l][0] = s;
      sred[wm][wn*64 + n*16 + l][1] = qq;
    }
  }
  __syncthreads();
  if (tid < BN) {
    float S = sred[0][tid][0] + sred[1][tid][0];
    float Q = sred[0][tid][1] + sred[1][tid][1];
    part[((size_t)rt * NTOT + ct*BN + tid) * 2 + 0] = S;
    part[((size_t)rt * NTOT + ct*BN + tid) * 2 + 1] = Q;
  }
}

// ---------------- finalize: per-channel partials -> (a,b) BN coeffs -------
__global__ void finalize_stats(const float* __restrict__ part,
                               const float* __restrict__ g,
                               const float* __restrict__ be,
                               float* __restrict__ ab, int nrt, int C, float invM)
{
  const int c = blockIdx.x;
  const int t = threadIdx.x;
  float s = 0.f, q = 0.f;
  for (int r = t; r < nrt; r += 64) {
    s += part[((size_t)r * C + c) * 2 + 0];
    q += part[((size_t)r * C + c) * 2 + 1];
  }
  #pragma unroll
  for (int o = 32; o > 0; o >>= 1) { s += __shfl_down(s, o); q += __shfl_down(q, o); }
  if (t == 0) {
    float mean = s * invM;
    float var  = q * invM - mean * mean;
    float rstd = rsqrtf(var + 1e-5f);
    float a = g[c] * rstd;
    ab[c*2 + 0] = a;
    ab[c*2 + 1] = be[c] - mean * a;
  }
}

// ---------------- elementwise BN+ReLU (bf16 in -> fp32 out) ----------------
__global__ __launch_bounds__(256) void bnrelu_out(
    const unsigned short* __restrict__ Y, const float* __restrict__ ab,
    float* __restrict__ out)
{
  __shared__ float sa[H2_], sb[H2_];
  if (threadIdx.x < H2_) { sa[threadIdx.x] = ab[threadIdx.x*2]; sb[threadIdx.x] = ab[threadIdx.x*2+1]; }
  __syncthreads();
  const size_t total = (size_t)ROWS_ * H2_ / 8;
  for (size_t i = (size_t)blockIdx.x*256 + threadIdx.x; i < total; i += (size_t)gridDim.x*256) {
    u16x8 v = ((const u16x8*)Y)[i];
    int cb = (int)((i * 8) & (H2_ - 1));
    float4 o0, o1;
    o0.x = fmaxf(fmaf(bf2f((unsigned short)v[0]), sa[cb+0], sb[cb+0]), 0.f);
    o0.y = fmaxf(fmaf(bf2f((unsigned short)v[1]), sa[cb+1], sb[cb+1]), 0.f);
    o0.z = fmaxf(fmaf(bf2f((unsigned short)v[2]), sa[cb+2], sb[cb+2]), 0.f);
    o0.w = fmaxf(fmaf(bf2f((unsigned short)v[3]), sa[cb+3], sb[cb+3]), 0.f);
    o1.x = fmaxf(fmaf(bf2f((unsigned short)v[4]), sa[cb+4], sb[cb+4]), 0.f);
    o1.y = fmaxf(fmaf(bf2f((unsigned short)v[5]), sa[cb+5], sb[cb+5]), 0.f);
    o1.z = fmaxf(fmaf(bf2f((unsigned short)v[6]), sa[cb+6], sb[cb+6]), 0.f);
    o1.w = fmaxf(fmaf(bf2f((unsigned short)v[7]), sa[cb+7], sb[cb+7]), 0.f);
    ((float4*)out)[i*2]   = o0;
    ((float4*)out)[i*2+1] = o1;
  }
}

// ---------------- launch -------------------------------------------------
extern "C" void kernel_launch(void* const* d_in, const int* in_sizes, int n_in,
                              void* d_out, int out_size, void* d_ws, size_t ws_size,
                              hipStream_t stream)
{
  const float* xyzf = (const float*)d_in[0];
  const float* xyzc = (const float*)d_in[1];
  const float* ff   = (const float*)d_in[2];
  const float* fc   = (const float*)d_in[3];
  const float* W1   = (const float*)d_in[4];
  // d_in[5] = b1 : cancels inside BatchNorm
  const float* g1   = (const float*)d_in[6];
  const float* be1  = (const float*)d_in[7];
  const float* W2   = (const float*)d_in[8];
  // d_in[9] = b2 : cancels inside BatchNorm
  const float* g2   = (const float*)d_in[10];
  const float* be2  = (const float*)d_in[11];
  float* out = (float*)d_out;

  char* ws = (char*)d_ws;
  // layout (bytes), all 256-aligned. Lifetime-based aliasing:
  //  X  @229376 : written nn_finish, read gemm1, then DEAD
  //  Y2b@229376 : written gemm2 (after gemm1 done), read bnrelu_out [alias X]
  //  fcb@42172416: written prep, read nn_finish, then DEAD
  //  Y1 @42172416: written gemm1 (after nn_finish), read gemm2     [alias fcb]
  unsigned short* W1b  = (unsigned short*)(ws + 0);          // 163840
  unsigned short* W2b  = (unsigned short*)(ws + 163840);     // 65536
  unsigned short* X    = (unsigned short*)(ws + 229376);     // 41943040
  unsigned short* Y2b  = (unsigned short*)(ws + 229376);     // 16777216 (alias X)
  unsigned short* fcb  = (unsigned short*)(ws + 42172416);   // 8388608
  unsigned short* Y1   = (unsigned short*)(ws + 42172416);   // 33554432 (alias fcb)
  float* part1 = (float*)(ws + 75726848);                    // 1048576
  float* part2 = (float*)(ws + 76775424);                    // 524288
  float* ab1   = (float*)(ws + 77299712);                    // 2048
  float* ab2   = (float*)(ws + 77301760);                    // 1024
  float4* cpk  = (float4*)(ws + 77302784);                   // 262144
  float4* pdw  = (float4*)(ws + 77564928);                   // 4194304 (SPLIT=4)
  int4*   piw  = (int4*)  (ws + 85953536);                   // 4194304

  prep<<<1024, 256, 0, stream>>>(W1, W2, xyzc, fc, W1b, W2b, cpk, fcb);
  nn_scan<<<B_ * 64 * SPLIT_, 256, 0, stream>>>(xyzf, cpk, pdw, piw);
  nn_finish<<<B_ * 256, 256, 0, stream>>>(pdw, piw, ff, fcb, X);

  // layer 1: y1 = X @ W1^T  (M=65536, N=256, K=320), stats fused
  gemm_stats<CIN_, H1_, true><<<(ROWS_/128) * (H1_/128), 256, 0, stream>>>(
      X, W1b, Y1, nullptr, part1);
  finalize_stats<<<H1_, 64, 0, stream>>>(part1, g1, be1, ab1, ROWS_/128, H1_, 1.f/ROWS_);

  // layer 2: y2 = relu(bn1(Y1)) @ W2^T with BN+ReLU fused into the A-load
  gemm_bnrelu_stats<H1_, H2_><<<(ROWS_/128) * (H2_/128), 256, 0, stream>>>(
      Y1, ab1, W2b, Y2b, part2);
  finalize_stats<<<H2_, 64, 0, stream>>>(part2, g2, be2, ab2, ROWS_/128, H2_, 1.f/ROWS_);
  bnrelu_out<<<2048, 256, 0, stream>>>(Y2b, ab2, out);
}